// Round 2
// baseline (16243.021 us; speedup 1.0000x reference)
//
#include <hip/hip_runtime.h>

#define B_ 8
#define R_ 128
#define T_ 64
#define FIN_ 32
#define L_ 64
#define D_ 64
#define H_ 128
#define OUT_ 32
#define ES_ 2048

__device__ __forceinline__ float silu_f(float x) { return x / (1.f + __expf(-x)); }
__device__ __forceinline__ float tanh_f(float x) {
    float e = __expf(2.f * x);
    return 1.f - 2.f / (e + 1.f);
}

// ---------------------------------------------------------------------------
// prep: deterministic CSR (edges sorted by dst, stable) + permuted per-batch
// edge weights + degree-serpentine row permutation prow (balances gather
// waves: rank r by degree desc, pos = (rank&15)*8 + (rank>>4) so each group
// of 8 consecutive slots spans the degree spectrum).
// ---------------------------------------------------------------------------
__global__ __launch_bounds__(128) void prep_kernel(
    const int* __restrict__ src, const int* __restrict__ dst,
    const float* __restrict__ space_w,
    int* __restrict__ row_start, int* __restrict__ esrcp, float* __restrict__ wperm,
    int* __restrict__ prow) {
    __shared__ int cnt[R_];
    __shared__ int rs[R_ + 1];
    __shared__ int permS[ES_];
    int r = threadIdx.x;
    int c = 0;
    for (int e = 0; e < ES_; ++e) c += (dst[e] == r) ? 1 : 0;
    cnt[r] = c;
    __syncthreads();
    if (r == 0) {
        int a = 0;
        for (int i = 0; i < R_; ++i) { rs[i] = a; a += cnt[i]; }
        rs[R_] = a;
    }
    __syncthreads();
    {
        int k = rs[r];
        for (int e = 0; e < ES_; ++e)
            if (dst[e] == r) permS[k++] = e;
    }
    __syncthreads();
    row_start[r] = rs[r];
    if (r == 0) row_start[R_] = rs[R_];
    // degree-serpentine permutation
    {
        int rank = 0;
        for (int i = 0; i < R_; ++i) {
            int ci = cnt[i];
            rank += (ci > c || (ci == c && i < r)) ? 1 : 0;
        }
        int pos = ((rank & 15) << 3) | (rank >> 4);
        prow[pos] = r;
    }
    for (int e = r; e < ES_; e += 128) esrcp[e] = src[permS[e]];
    for (int i = r; i < B_ * ES_; i += 128) {
        int b = i >> 11;
        int e = i & (ES_ - 1);
        wperm[i] = space_w[b * ES_ + permS[e]];
    }
}

// ---------------------------------------------------------------------------
// encoder: one block per (b,r).
// ---------------------------------------------------------------------------
__global__ __launch_bounds__(256) void encoder_kernel(
    const float* __restrict__ node_feats, const float* __restrict__ eps,
    const float* __restrict__ W_e1, const float* __restrict__ b_e1,
    const float* __restrict__ W_e2, const float* __restrict__ b_e2,
    const float* __restrict__ W_mu, const float* __restrict__ W_sig,
    const float* __restrict__ W_dyn,
    float* __restrict__ Lz, float* __restrict__ Dz, float* __restrict__ dynb) {
    int br = blockIdx.x;
    int tid = threadIdx.x;
    __shared__ float xS[T_ * 33];
    __shared__ float we1[33 * H_];
    __shared__ __align__(16) float h1[T_ * H_];
    __shared__ float hps[2 * H_];
    __shared__ float hp[H_];
    __shared__ float muS[H_], sgS[H_], vS[H_];

    const float* nf = node_feats + (size_t)br * (T_ * FIN_);
    for (int i = tid; i < T_ * FIN_; i += 256) {
        int t = i >> 5, f = i & 31;
        xS[t * 33 + f] = nf[i];
    }
    if (tid < T_) xS[tid * 33 + 32] = (float)tid * (1.f / 64.f);
    for (int i = tid; i < 33 * H_; i += 256) we1[i] = W_e1[i];
    __syncthreads();

    int j = tid & 127;
    int th = tid >> 7;
    float be1 = b_e1[j];
    for (int tt = 0; tt < 32; ++tt) {
        int t = th * 32 + tt;
        float a = be1;
        #pragma unroll
        for (int k = 0; k < 33; ++k) a += xS[t * 33 + k] * we1[k * H_ + j];
        h1[t * H_ + j] = silu_f(a);
    }
    __syncthreads();

    float acc[32];
    float be2 = b_e2[j];
    #pragma unroll
    for (int tt = 0; tt < 32; ++tt) acc[tt] = be2;
    for (int kc = 0; kc < 4; ++kc) {
        float wreg[32];
        #pragma unroll
        for (int i2 = 0; i2 < 32; ++i2) wreg[i2] = W_e2[(kc * 32 + i2) * H_ + j];
        #pragma unroll
        for (int tt = 0; tt < 32; ++tt) {
            int t = th * 32 + tt;
            const float4* hrow = (const float4*)(&h1[t * H_ + kc * 32]);
            float s = 0.f;
            #pragma unroll
            for (int w4 = 0; w4 < 8; ++w4) {
                float4 hv = hrow[w4];
                s += hv.x * wreg[w4 * 4 + 0] + hv.y * wreg[w4 * 4 + 1] +
                     hv.z * wreg[w4 * 4 + 2] + hv.w * wreg[w4 * 4 + 3];
            }
            acc[tt] += s;
        }
    }
    float msum = 0.f;
    #pragma unroll
    for (int tt = 0; tt < 32; ++tt) msum += silu_f(acc[tt]);
    hps[th * H_ + j] = msum;
    __syncthreads();
    if (tid < H_) hp[tid] = (hps[tid] + hps[H_ + tid]) * (1.f / 64.f);
    __syncthreads();

    {
        const float* Wm = (th == 0) ? W_mu : W_sig;
        float a = 0.f;
        #pragma unroll 4
        for (int k = 0; k < H_; ++k) a += hp[k] * Wm[k * H_ + j];
        if (th == 0) muS[j] = a; else sgS[j] = a;
    }
    __syncthreads();
    if (tid < H_) {
        float sig = 0.1f + 0.9f / (1.f + __expf(-sgS[tid]));
        float v = muS[tid] + sig * eps[(size_t)br * H_ + tid];
        vS[tid] = v;
        if (tid < L_) Lz[(size_t)br * L_ + tid] = v;
        else          Dz[(size_t)br * D_ + (tid - L_)] = v;
    }
    __syncthreads();
    if (tid < L_) {
        float a = 0.f;
        #pragma unroll 4
        for (int k = 0; k < D_; ++k) a += vS[L_ + k] * W_dyn[k * L_ + tid];
        dynb[(size_t)br * L_ + tid] = a;
    }
}

// ---------------------------------------------------------------------------
// ode: one block per batch. Two thread mappings per stage:
//  gather: thread (vr=tid>>3, g=tid&7) -> actual row ar=prow[vr], feats 8g..8g+8
//  GEMM/state: wave wv=tid>>6 owns cols j0=(wv>>1)*8 (wave-uniform -> weights
//  via s_load SGPR broadcast), rows rb=(wv&1)*64+lane; thread owns out/state
//  (rb, j0..j0+8). xstage double-buffered (ping-pong) -> 2 barriers/stage.
// ---------------------------------------------------------------------------
#define XPAD 68
__global__ __launch_bounds__(1024) void ode_kernel(
    const float* __restrict__ Lz, const float* __restrict__ dynb,
    const float* __restrict__ W_msg, const float* __restrict__ W_self,
    const float* __restrict__ b_ode,
    const int* __restrict__ row_start, const int* __restrict__ esrcp,
    const float* __restrict__ wperm, const int* __restrict__ prow,
    float* __restrict__ traj) {
    const int b = blockIdx.x;
    const int tid = threadIdx.x;
    const int lane = tid & 63;
    const int rb = ((tid >> 6) & 1) * 64 + lane;           // state row
    const int j0 = __builtin_amdgcn_readfirstlane((int)(threadIdx.x >> 7)) << 3;  // wave-uniform col base
    const int vr = tid >> 3;                                // gather row slot
    const int gf0 = (tid & 7) << 3;                         // gather feat base

    extern __shared__ float lds[];
    float* xbuf0 = lds;                                     // 128*68
    float* xbuf1 = xbuf0 + 128 * XPAD;                      // 128*68
    float* aggl  = xbuf1 + 128 * XPAD;                      // 128*68
    float* ewS   = aggl + 128 * XPAD;                       // 2048
    int*   esS   = (int*)(ewS + ES_);                       // 2048
    int*   rsS   = esS + ES_;                               // 129 (+pad)
    int*   prS   = rsS + 132;                               // 128

    for (int i = tid; i < ES_; i += 1024) {
        ewS[i] = wperm[b * ES_ + i];
        esS[i] = esrcp[i];
    }
    if (tid <= R_) rsS[tid] = row_start[tid];
    if (tid < R_) prS[tid] = prow[tid];

    float xb[8], ks[8], dnb[8];
    {
        const float4* lp = (const float4*)(Lz + ((size_t)(b * R_ + rb)) * L_ + j0);
        float4 l0 = lp[0], l1 = lp[1];
        xb[0] = l0.x; xb[1] = l0.y; xb[2] = l0.z; xb[3] = l0.w;
        xb[4] = l1.x; xb[5] = l1.y; xb[6] = l1.z; xb[7] = l1.w;
        const float4* dp = (const float4*)(dynb + ((size_t)(b * R_ + rb)) * L_ + j0);
        float4 d0 = dp[0], d1 = dp[1];
        const float4* bp = (const float4*)(b_ode + j0);
        float4 o0 = bp[0], o1 = bp[1];
        dnb[0] = d0.x + o0.x; dnb[1] = d0.y + o0.y; dnb[2] = d0.z + o0.z; dnb[3] = d0.w + o0.w;
        dnb[4] = d1.x + o1.x; dnb[5] = d1.y + o1.y; dnb[6] = d1.z + o1.z; dnb[7] = d1.w + o1.w;
    }
    {
        float* xr = xbuf0 + rb * XPAD + j0;
        ((float4*)xr)[0] = make_float4(xb[0], xb[1], xb[2], xb[3]);
        ((float4*)xr)[1] = make_float4(xb[4], xb[5], xb[6], xb[7]);
    }
    __syncthreads();

    const int ar = prS[vr];
    const int rs0 = rsS[ar], rs1 = rsS[ar + 1];
    float* xc = xbuf0;
    float* xn = xbuf1;

    for (int n = 0; n < T_; ++n) {
        #pragma unroll
        for (int i = 0; i < 8; ++i) ks[i] = 0.f;
        #pragma unroll
        for (int s = 0; s < 4; ++s) {
            const float wk = (s == 1 || s == 2) ? 2.f : 1.f;
            const float cn = (s < 2) ? 0.05f : 0.1f;

            // ---- gather: aggl[ar][gf0..gf0+8) = sum_e w_e * xc[src_e][gf0..]
            float ag[8];
            #pragma unroll
            for (int i = 0; i < 8; ++i) ag[i] = 0.f;
            for (int e = rs0; e < rs1; ++e) {
                float w = ewS[e];
                int sn = esS[e];
                const float4* xr4 = (const float4*)(xc + sn * XPAD + gf0);
                float4 a0 = xr4[0], a1 = xr4[1];
                ag[0] += w * a0.x; ag[1] += w * a0.y; ag[2] += w * a0.z; ag[3] += w * a0.w;
                ag[4] += w * a1.x; ag[5] += w * a1.y; ag[6] += w * a1.z; ag[7] += w * a1.w;
            }
            {
                float* arw = aggl + ar * XPAD + gf0;
                ((float4*)arw)[0] = make_float4(ag[0], ag[1], ag[2], ag[3]);
                ((float4*)arw)[1] = make_float4(ag[4], ag[5], ag[6], ag[7]);
            }
            __syncthreads();

            // ---- GEMM: out[rb][j0+i] = sum_k aggl[rb][k]*Wmsg[k][j0+i]
            //                                + xc[rb][k]*Wself[k][j0+i]
            // weights wave-uniform -> scalar loads (SGPR broadcast)
            float acc[8];
            #pragma unroll
            for (int i = 0; i < 8; ++i) acc[i] = 0.f;
            {
                const float4* aRow = (const float4*)(aggl + rb * XPAD);
                const float4* xRow = (const float4*)(xc + rb * XPAD);
                #pragma unroll
                for (int kq = 0; kq < 16; ++kq) {
                    float4 av = aRow[kq];
                    float4 xv = xRow[kq];
                    #pragma unroll
                    for (int t = 0; t < 4; ++t) {
                        const int k = kq * 4 + t;
                        const float a_ = (t == 0) ? av.x : (t == 1) ? av.y : (t == 2) ? av.z : av.w;
                        const float x_ = (t == 0) ? xv.x : (t == 1) ? xv.y : (t == 2) ? xv.z : xv.w;
                        const float* wm = W_msg + k * 64 + j0;
                        const float* wsf = W_self + k * 64 + j0;
                        #pragma unroll
                        for (int i = 0; i < 8; ++i)
                            acc[i] += a_ * wm[i] + x_ * wsf[i];
                    }
                }
            }
            float kv[8];
            #pragma unroll
            for (int i = 0; i < 8; ++i) {
                kv[i] = tanh_f(acc[i] + dnb[i]);
                ks[i] += wk * kv[i];
            }
            float* xnr = xn + rb * XPAD + j0;
            if (s < 3) {
                ((float4*)xnr)[0] = make_float4(xb[0] + cn * kv[0], xb[1] + cn * kv[1],
                                                xb[2] + cn * kv[2], xb[3] + cn * kv[3]);
                ((float4*)xnr)[1] = make_float4(xb[4] + cn * kv[4], xb[5] + cn * kv[5],
                                                xb[6] + cn * kv[6], xb[7] + cn * kv[7]);
            } else {
                #pragma unroll
                for (int i = 0; i < 8; ++i) xb[i] += (0.1f / 6.f) * ks[i];
                ((float4*)xnr)[0] = make_float4(xb[0], xb[1], xb[2], xb[3]);
                ((float4*)xnr)[1] = make_float4(xb[4], xb[5], xb[6], xb[7]);
                float* tp = traj + (((size_t)b * T_ + n) * R_ + rb) * L_ + j0;
                ((float4*)tp)[0] = make_float4(xb[0], xb[1], xb[2], xb[3]);
                ((float4*)tp)[1] = make_float4(xb[4], xb[5], xb[6], xb[7]);
            }
            __syncthreads();
            float* tswp = xc; xc = xn; xn = tswp;
        }
    }
}

// ---------------------------------------------------------------------------
// decoder: one block per (b,r), one-hot rid exploited as row lookup.
// ---------------------------------------------------------------------------
__global__ __launch_bounds__(256) void decoder_kernel(
    const float* __restrict__ traj, const float* __restrict__ Dz,
    const float* __restrict__ W_d1, const float* __restrict__ b_d1,
    const float* __restrict__ W_d2, const float* __restrict__ b_d2,
    float* __restrict__ y) {
    int br = blockIdx.x;
    int b = br >> 7;
    int r = br & 127;
    int tid = threadIdx.x;
    __shared__ __align__(16) float trajS[32 * L_];
    __shared__ __align__(16) float hS[32 * H_];
    __shared__ float dzS[D_];
    __shared__ float baseS[H_];

    int j = tid & 127;
    int th = tid >> 7;
    if (tid < D_) dzS[tid] = Dz[(size_t)br * D_ + tid];
    __syncthreads();

    float wcol[64];
    #pragma unroll
    for (int k = 0; k < 64; ++k) wcol[k] = W_d1[k * H_ + j];
    float wt = W_d1[128 * H_ + j];
    if (th == 0) {
        float a = b_d1[j] + W_d1[(129 + r) * H_ + j];
        #pragma unroll 4
        for (int k = 0; k < D_; ++k) a += dzS[k] * W_d1[(64 + k) * H_ + j];
        baseS[j] = a;
    }
    __syncthreads();
    float bb = baseS[j];

    for (int half = 0; half < 2; ++half) {
        for (int i = tid; i < 32 * L_; i += 256) {
            int tt = i >> 6, l = i & 63;
            trajS[i] = traj[(((size_t)b * T_ + half * 32 + tt) * R_ + r) * L_ + l];
        }
        __syncthreads();
        #pragma unroll
        for (int tt = 0; tt < 16; ++tt) {
            int tl = th * 16 + tt;
            int t = half * 32 + tl;
            float a = bb + (float)t * (1.f / 64.f) * wt;
            const float4* tr4 = (const float4*)(&trajS[tl * L_]);
            #pragma unroll
            for (int kb = 0; kb < 16; ++kb) {
                float4 tv = tr4[kb];
                a += tv.x * wcol[kb * 4 + 0] + tv.y * wcol[kb * 4 + 1] +
                     tv.z * wcol[kb * 4 + 2] + tv.w * wcol[kb * 4 + 3];
            }
            hS[tl * H_ + j] = silu_f(a);
        }
        __syncthreads();
        {
            int o = tid & 31, q = tid >> 5;
            float acc2[4];
            float bd2 = b_d2[o];
            #pragma unroll
            for (int u = 0; u < 4; ++u) acc2[u] = bd2;
            for (int jc = 0; jc < 4; ++jc) {
                float wreg[32];
                #pragma unroll
                for (int i2 = 0; i2 < 32; ++i2) wreg[i2] = W_d2[(jc * 32 + i2) * OUT_ + o];
                #pragma unroll
                for (int u = 0; u < 4; ++u) {
                    int tl = q * 4 + u;
                    const float4* h4 = (const float4*)(&hS[tl * H_ + jc * 32]);
                    float s2 = 0.f;
                    #pragma unroll
                    for (int w4 = 0; w4 < 8; ++w4) {
                        float4 hv = h4[w4];
                        s2 += hv.x * wreg[w4 * 4 + 0] + hv.y * wreg[w4 * 4 + 1] +
                              hv.z * wreg[w4 * 4 + 2] + hv.w * wreg[w4 * 4 + 3];
                    }
                    acc2[u] += s2;
                }
            }
            #pragma unroll
            for (int u = 0; u < 4; ++u) {
                int t = half * 32 + q * 4 + u;
                y[((size_t)br * T_ + t) * OUT_ + o] = acc2[u];
            }
        }
        __syncthreads();
    }
}

extern "C" void kernel_launch(void* const* d_in, const int* in_sizes, int n_in,
                              void* d_out, int out_size, void* d_ws, size_t ws_size,
                              hipStream_t stream) {
    const float* node_feats = (const float*)d_in[0];
    const float* eps_       = (const float*)d_in[1];
    const float* space_w    = (const float*)d_in[2];
    const int*   src        = (const int*)d_in[3];
    const int*   dst        = (const int*)d_in[4];
    const float* W_e1 = (const float*)d_in[5];
    const float* b_e1 = (const float*)d_in[6];
    const float* W_e2 = (const float*)d_in[7];
    const float* b_e2 = (const float*)d_in[8];
    const float* W_mu = (const float*)d_in[9];
    const float* W_sig = (const float*)d_in[10];
    const float* W_msg = (const float*)d_in[11];
    const float* W_self = (const float*)d_in[12];
    const float* W_dyn = (const float*)d_in[13];
    const float* b_ode = (const float*)d_in[14];
    const float* W_d1 = (const float*)d_in[15];
    const float* b_d1 = (const float*)d_in[16];
    const float* W_d2 = (const float*)d_in[17];
    const float* b_d2 = (const float*)d_in[18];
    float* out = (float*)d_out;

    float* f_ws = (float*)d_ws;
    float* Lz    = f_ws;                              // 65536
    float* Dz    = Lz + B_ * R_ * L_;                 // 65536
    float* dynb  = Dz + B_ * R_ * D_;                 // 65536
    float* traj  = dynb + B_ * R_ * L_;               // 4194304
    float* wperm = traj + (size_t)B_ * T_ * R_ * L_;  // 16384
    int* row_start = (int*)(wperm + B_ * ES_);        // 132
    int* esrcp     = row_start + 132;                 // 2048
    int* prow      = esrcp + ES_;                     // 128

    prep_kernel<<<1, 128, 0, stream>>>(src, dst, space_w, row_start, esrcp, wperm, prow);
    encoder_kernel<<<B_ * R_, 256, 0, stream>>>(node_feats, eps_, W_e1, b_e1, W_e2, b_e2,
                                                W_mu, W_sig, W_dyn, Lz, Dz, dynb);
    size_t ode_lds = (size_t)(3 * 128 * XPAD + ES_) * sizeof(float) +
                     (size_t)(ES_ + 132 + 128) * sizeof(int);
    ode_kernel<<<B_, 1024, ode_lds, stream>>>(Lz, dynb, W_msg, W_self, b_ode,
                                              row_start, esrcp, wperm, prow, traj);
    decoder_kernel<<<B_ * R_, 256, 0, stream>>>(traj, Dz, W_d1, b_d1, W_d2, b_d2, out);
}

// Round 3
// 1650.343 us; speedup vs baseline: 9.8422x; 9.8422x over previous
//
#include <hip/hip_runtime.h>

#define B_ 8
#define R_ 128
#define T_ 64
#define FIN_ 32
#define L_ 64
#define D_ 64
#define H_ 128
#define OUT_ 32
#define ES_ 2048

typedef _Float16 f16;
typedef __attribute__((ext_vector_type(4))) _Float16 f16x4;
typedef __attribute__((ext_vector_type(8))) _Float16 f16x8;
typedef __attribute__((ext_vector_type(16))) float f32x16;

__device__ __forceinline__ float silu_f(float x) { return x / (1.f + __expf(-x)); }
__device__ __forceinline__ float tanh_f(float x) {
    float e = __expf(2.f * x);
    return 1.f - 2.f / (e + 1.f);
}

// LDS byte-offset swizzles: XOR a row-derived value into the 16B-granule bits.
// 256B-stride arrays ([dim][2][64] f16): rows fully spread over 16 granules.
__device__ __forceinline__ uint32_t swz256(uint32_t row, uint32_t s, uint32_t colByte) {
    uint32_t bo = row * 256u + s * 128u + colByte;
    return bo ^ ((row & 15u) << 4);
}
// xT ([64 c][2][128 r] f16, 512B rows): spread over 32 granules.
__device__ __forceinline__ uint32_t swzT(uint32_t c, uint32_t s, uint32_t rByte) {
    uint32_t bo = c * 512u + s * 256u + rByte;
    return bo ^ ((c & 31u) << 4);
}

#define XROW_OFF 0u        // 32 KB: x row-major   [128 r][2 s][64 c] f16
#define XT_OFF   32768u    // 32 KB: x col-major   [64 c][2 s][128 r] f16
#define AGG_OFF  65536u    // 32 KB: agg row-major [128 r][2 s][64 c] f16
#define WM_OFF   98304u    // 16 KB: Wmsg^T  [64 j][2 s][64 k] f16
#define WS_OFF   114688u   // 16 KB: Wself^T [64 j][2 s][64 k] f16
#define ODE_LDS  131072u

// ---------------------------------------------------------------------------
// prep: deterministic CSR (edges sorted by dst, stable) + permuted per-batch
// edge weights.
// ---------------------------------------------------------------------------
__global__ __launch_bounds__(128) void prep_kernel(
    const int* __restrict__ src, const int* __restrict__ dst,
    const float* __restrict__ space_w,
    int* __restrict__ row_start, int* __restrict__ esrcp, float* __restrict__ wperm) {
    __shared__ int cnt[R_];
    __shared__ int rs[R_ + 1];
    __shared__ int permS[ES_];
    int r = threadIdx.x;
    int c = 0;
    for (int e = 0; e < ES_; ++e) c += (dst[e] == r) ? 1 : 0;
    cnt[r] = c;
    __syncthreads();
    if (r == 0) {
        int a = 0;
        for (int i = 0; i < R_; ++i) { rs[i] = a; a += cnt[i]; }
        rs[R_] = a;
    }
    __syncthreads();
    {
        int k = rs[r];
        for (int e = 0; e < ES_; ++e)
            if (dst[e] == r) permS[k++] = e;
    }
    __syncthreads();
    row_start[r] = rs[r];
    if (r == 0) row_start[R_] = rs[R_];
    for (int e = r; e < ES_; e += 128) esrcp[e] = src[permS[e]];
    for (int i = r; i < B_ * ES_; i += 128) {
        int b = i >> 11;
        int e = i & (ES_ - 1);
        wperm[i] = space_w[b * ES_ + permS[e]];
    }
}

// ---------------------------------------------------------------------------
// encoder: one block per (b,r).
// ---------------------------------------------------------------------------
__global__ __launch_bounds__(256) void encoder_kernel(
    const float* __restrict__ node_feats, const float* __restrict__ eps,
    const float* __restrict__ W_e1, const float* __restrict__ b_e1,
    const float* __restrict__ W_e2, const float* __restrict__ b_e2,
    const float* __restrict__ W_mu, const float* __restrict__ W_sig,
    const float* __restrict__ W_dyn,
    float* __restrict__ Lz, float* __restrict__ Dz, float* __restrict__ dynb) {
    int br = blockIdx.x;
    int tid = threadIdx.x;
    __shared__ float xS[T_ * 33];
    __shared__ float we1[33 * H_];
    __shared__ __align__(16) float h1[T_ * H_];
    __shared__ float hps[2 * H_];
    __shared__ float hp[H_];
    __shared__ float muS[H_], sgS[H_], vS[H_];

    const float* nf = node_feats + (size_t)br * (T_ * FIN_);
    for (int i = tid; i < T_ * FIN_; i += 256) {
        int t = i >> 5, f = i & 31;
        xS[t * 33 + f] = nf[i];
    }
    if (tid < T_) xS[tid * 33 + 32] = (float)tid * (1.f / 64.f);
    for (int i = tid; i < 33 * H_; i += 256) we1[i] = W_e1[i];
    __syncthreads();

    int j = tid & 127;
    int th = tid >> 7;
    float be1 = b_e1[j];
    for (int tt = 0; tt < 32; ++tt) {
        int t = th * 32 + tt;
        float a = be1;
        #pragma unroll
        for (int k = 0; k < 33; ++k) a += xS[t * 33 + k] * we1[k * H_ + j];
        h1[t * H_ + j] = silu_f(a);
    }
    __syncthreads();

    float acc[32];
    float be2 = b_e2[j];
    #pragma unroll
    for (int tt = 0; tt < 32; ++tt) acc[tt] = be2;
    for (int kc = 0; kc < 4; ++kc) {
        float wreg[32];
        #pragma unroll
        for (int i2 = 0; i2 < 32; ++i2) wreg[i2] = W_e2[(kc * 32 + i2) * H_ + j];
        #pragma unroll
        for (int tt = 0; tt < 32; ++tt) {
            int t = th * 32 + tt;
            const float4* hrow = (const float4*)(&h1[t * H_ + kc * 32]);
            float s = 0.f;
            #pragma unroll
            for (int w4 = 0; w4 < 8; ++w4) {
                float4 hv = hrow[w4];
                s += hv.x * wreg[w4 * 4 + 0] + hv.y * wreg[w4 * 4 + 1] +
                     hv.z * wreg[w4 * 4 + 2] + hv.w * wreg[w4 * 4 + 3];
            }
            acc[tt] += s;
        }
    }
    float msum = 0.f;
    #pragma unroll
    for (int tt = 0; tt < 32; ++tt) msum += silu_f(acc[tt]);
    hps[th * H_ + j] = msum;
    __syncthreads();
    if (tid < H_) hp[tid] = (hps[tid] + hps[H_ + tid]) * (1.f / 64.f);
    __syncthreads();

    {
        const float* Wm = (th == 0) ? W_mu : W_sig;
        float a = 0.f;
        #pragma unroll 4
        for (int k = 0; k < H_; ++k) a += hp[k] * Wm[k * H_ + j];
        if (th == 0) muS[j] = a; else sgS[j] = a;
    }
    __syncthreads();
    if (tid < H_) {
        float sig = 0.1f + 0.9f / (1.f + __expf(-sgS[tid]));
        float v = muS[tid] + sig * eps[(size_t)br * H_ + tid];
        vS[tid] = v;
        if (tid < L_) Lz[(size_t)br * L_ + tid] = v;
        else          Dz[(size_t)br * D_ + (tid - L_)] = v;
    }
    __syncthreads();
    if (tid < L_) {
        float a = 0.f;
        #pragma unroll 4
        for (int k = 0; k < D_; ++k) a += vS[L_ + k] * W_dyn[k * L_ + tid];
        dynb[(size_t)br * L_ + tid] = a;
    }
}

// ---------------------------------------------------------------------------
// ode (MFMA): one block per batch, 8 waves. Per stage:
//   phase1: agg = A@x (A-frags in VGPR, x from xT) ; accK = x@Wself (+dyn)
//           write agg hi/lo to LDS
//   phase2: accK += agg@Wmsg ; kv = tanh(accK) ; RK4 update ; write new x
// All GEMM inputs fp16 hi/lo, 3-product emulation (hi*hi + lo*hi + hi*lo).
// Thread state lives in the 32x32 MFMA C-layout:
//   c = cb*32 + (lane&31), r(i) = rb*32 + (i&3) + 8*(i>>2) + 4*(lane>>5)
// ---------------------------------------------------------------------------
__global__ __launch_bounds__(512, 2) void ode_kernel(
    const float* __restrict__ Lz, const float* __restrict__ dynb,
    const float* __restrict__ W_msg, const float* __restrict__ W_self,
    const float* __restrict__ b_ode,
    const int* __restrict__ row_start, const int* __restrict__ esrcp,
    const float* __restrict__ wperm,
    float* __restrict__ traj) {
    const int b = blockIdx.x;
    const int tid = threadIdx.x;
    const int lane = tid & 63;
    const int w = tid >> 6;          // 0..7
    const int rb = w & 3;            // output row block (32 rows)
    const int cb = w >> 2;           // output col block (32 cols)
    const int l31 = lane & 31;
    const int h = lane >> 5;
    const int cc = cb * 32 + l31;    // this thread's output column

    extern __shared__ char sm[];
    float* Af = (float*)sm;          // fp32 A staging [128][128], overlaps XROW/XT pre-loop

    // ---- static weights -> LDS (hi/lo, transposed: WT[j][s][k] = W[k][j]) ----
    for (int idx = tid; idx < 4096; idx += 512) {
        int j = idx & 63, k = idx >> 6;
        float vm = W_msg[k * 64 + j];
        f16 mh = (f16)vm;
        *(f16*)(sm + WM_OFF + swz256(j, 0, k * 2)) = mh;
        *(f16*)(sm + WM_OFF + swz256(j, 1, k * 2)) = (f16)(vm - (float)mh);
        float vs = W_self[k * 64 + j];
        f16 sh = (f16)vs;
        *(f16*)(sm + WS_OFF + swz256(j, 0, k * 2)) = sh;
        *(f16*)(sm + WS_OFF + swz256(j, 1, k * 2)) = (f16)(vs - (float)sh);
    }
    // ---- zero A, then deterministic CSR build ----
    for (int i = tid; i < 128 * 128; i += 512) Af[i] = 0.f;
    __syncthreads();
    if (tid < 128) {
        int e0 = row_start[tid], e1 = row_start[tid + 1];
        for (int e = e0; e < e1; ++e)
            Af[tid * 128 + esrcp[e]] += wperm[b * ES_ + e];
    }
    __syncthreads();

    // ---- A fragments -> VGPRs (hi/lo), one 32-row block per wave ----
    f16x8 aH[8], aL[8];
    {
        int row = rb * 32 + l31;
        #pragma unroll
        for (int m = 0; m < 8; ++m) {
            const float* p = Af + row * 128 + m * 16 + h * 8;
            f16x8 vh, vl;
            #pragma unroll
            for (int i = 0; i < 8; ++i) {
                float v = p[i];
                f16 hi = (f16)v;
                vh[i] = hi;
                vl[i] = (f16)(v - (float)hi);
            }
            aH[m] = vh;
            aL[m] = vl;
        }
    }

    // ---- per-thread state in C-layout ----
    float xb[16], ks[16], dnb[16];
    {
        float bo = b_ode[cc];
        #pragma unroll
        for (int i = 0; i < 16; ++i) {
            int r = rb * 32 + (i & 3) + 8 * (i >> 2) + 4 * h;
            size_t o = ((size_t)(b * R_ + r)) * L_ + cc;
            xb[i] = Lz[o];
            dnb[i] = dynb[o] + bo;
        }
    }
    __syncthreads();  // Af dead from here

    // ---- write initial x (xrow + xT, hi/lo) ----
    {
        #pragma unroll
        for (int i = 0; i < 16; ++i) {
            int r = rb * 32 + (i & 3) + 8 * (i >> 2) + 4 * h;
            f16 hi = (f16)xb[i];
            *(f16*)(sm + XROW_OFF + swz256(r, 0, cc * 2)) = hi;
            *(f16*)(sm + XROW_OFF + swz256(r, 1, cc * 2)) = (f16)(xb[i] - (float)hi);
        }
        #pragma unroll
        for (int q = 0; q < 4; ++q) {
            int rbase = rb * 32 + 8 * q + 4 * h;
            f16x4 vh, vl;
            #pragma unroll
            for (int u = 0; u < 4; ++u) {
                float t = xb[4 * q + u];
                f16 hi = (f16)t;
                vh[u] = hi;
                vl[u] = (f16)(t - (float)hi);
            }
            *(f16x4*)(sm + XT_OFF + swzT(cc, 0, rbase * 2)) = vh;
            *(f16x4*)(sm + XT_OFF + swzT(cc, 1, rbase * 2)) = vl;
        }
    }
    __syncthreads();

    const int rowx = rb * 32 + l31;   // A-operand row for this lane (self/agg frags)

    for (int n = 0; n < T_; ++n) {
        #pragma unroll
        for (int i = 0; i < 16; ++i) ks[i] = 0.f;
        for (int s4 = 0; s4 < 4; ++s4) {
            const float wk = (s4 == 1 || s4 == 2) ? 2.f : 1.f;
            const float cn = (s4 < 2) ? 0.05f : 0.1f;

            // ===== phase 1 =====
            // agg tile = A[rb-block] @ x[:, cb-block]   (K = 128 rows of x)
            f32x16 accA = {};
            #pragma unroll
            for (int m = 0; m < 8; ++m) {
                f16x8 btH = *(const f16x8*)(sm + XT_OFF + swzT(cc, 0, (m * 16 + 8 * h) * 2));
                f16x8 btL = *(const f16x8*)(sm + XT_OFF + swzT(cc, 1, (m * 16 + 8 * h) * 2));
                accA = __builtin_amdgcn_mfma_f32_32x32x16_f16(aH[m], btH, accA, 0, 0, 0);
                accA = __builtin_amdgcn_mfma_f32_32x32x16_f16(aL[m], btH, accA, 0, 0, 0);
                accA = __builtin_amdgcn_mfma_f32_32x32x16_f16(aH[m], btL, accA, 0, 0, 0);
            }
            // self-term: accK = dyn + x[rb-block,:] @ Wself[:, cb-block]  (K = 64 cols)
            f32x16 accK;
            #pragma unroll
            for (int i = 0; i < 16; ++i) accK[i] = dnb[i];
            #pragma unroll
            for (int m = 0; m < 4; ++m) {
                uint32_t kb = (m * 16 + 8 * h) * 2;
                f16x8 axH = *(const f16x8*)(sm + XROW_OFF + swz256(rowx, 0, kb));
                f16x8 axL = *(const f16x8*)(sm + XROW_OFF + swz256(rowx, 1, kb));
                f16x8 wsH = *(const f16x8*)(sm + WS_OFF + swz256(cc - cb * 32 + cb * 32, 0, kb));
                f16x8 wsL = *(const f16x8*)(sm + WS_OFF + swz256(cc, 1, kb));
                // note: WS rows indexed by output col j = cc (0..63)
                wsH = *(const f16x8*)(sm + WS_OFF + swz256(cc, 0, kb));
                accK = __builtin_amdgcn_mfma_f32_32x32x16_f16(axH, wsH, accK, 0, 0, 0);
                accK = __builtin_amdgcn_mfma_f32_32x32x16_f16(axL, wsH, accK, 0, 0, 0);
                accK = __builtin_amdgcn_mfma_f32_32x32x16_f16(axH, wsL, accK, 0, 0, 0);
            }
            // write agg hi/lo
            #pragma unroll
            for (int i = 0; i < 16; ++i) {
                int r = rb * 32 + (i & 3) + 8 * (i >> 2) + 4 * h;
                float v = accA[i];
                f16 hi = (f16)v;
                *(f16*)(sm + AGG_OFF + swz256(r, 0, cc * 2)) = hi;
                *(f16*)(sm + AGG_OFF + swz256(r, 1, cc * 2)) = (f16)(v - (float)hi);
            }
            __syncthreads();

            // ===== phase 2 =====
            // accK += agg[rb-block,:] @ Wmsg[:, cb-block]  (K = 64)
            #pragma unroll
            for (int m = 0; m < 4; ++m) {
                uint32_t kb = (m * 16 + 8 * h) * 2;
                f16x8 agH = *(const f16x8*)(sm + AGG_OFF + swz256(rowx, 0, kb));
                f16x8 agL = *(const f16x8*)(sm + AGG_OFF + swz256(rowx, 1, kb));
                f16x8 wmH = *(const f16x8*)(sm + WM_OFF + swz256(cc, 0, kb));
                f16x8 wmL = *(const f16x8*)(sm + WM_OFF + swz256(cc, 1, kb));
                accK = __builtin_amdgcn_mfma_f32_32x32x16_f16(agH, wmH, accK, 0, 0, 0);
                accK = __builtin_amdgcn_mfma_f32_32x32x16_f16(agL, wmH, accK, 0, 0, 0);
                accK = __builtin_amdgcn_mfma_f32_32x32x16_f16(agH, wmL, accK, 0, 0, 0);
            }
            // epilogue: tanh, RK4, write next x
            float xn_[16];
            #pragma unroll
            for (int i = 0; i < 16; ++i) {
                float kv = tanh_f(accK[i]);
                ks[i] += wk * kv;
                xn_[i] = (s4 < 3) ? (xb[i] + cn * kv) : (xb[i] + (0.1f / 6.f) * ks[i]);
            }
            if (s4 == 3) {
                #pragma unroll
                for (int i = 0; i < 16; ++i) xb[i] = xn_[i];
            }
            #pragma unroll
            for (int i = 0; i < 16; ++i) {
                int r = rb * 32 + (i & 3) + 8 * (i >> 2) + 4 * h;
                f16 hi = (f16)xn_[i];
                *(f16*)(sm + XROW_OFF + swz256(r, 0, cc * 2)) = hi;
                *(f16*)(sm + XROW_OFF + swz256(r, 1, cc * 2)) = (f16)(xn_[i] - (float)hi);
            }
            #pragma unroll
            for (int q = 0; q < 4; ++q) {
                int rbase = rb * 32 + 8 * q + 4 * h;
                f16x4 vh, vl;
                #pragma unroll
                for (int u = 0; u < 4; ++u) {
                    float t = xn_[4 * q + u];
                    f16 hi = (f16)t;
                    vh[u] = hi;
                    vl[u] = (f16)(t - (float)hi);
                }
                *(f16x4*)(sm + XT_OFF + swzT(cc, 0, rbase * 2)) = vh;
                *(f16x4*)(sm + XT_OFF + swzT(cc, 1, rbase * 2)) = vl;
            }
            if (s4 == 3) {
                #pragma unroll
                for (int i = 0; i < 16; ++i) {
                    int r = rb * 32 + (i & 3) + 8 * (i >> 2) + 4 * h;
                    traj[(((size_t)b * T_ + n) * R_ + r) * L_ + cc] = xb[i];
                }
            }
            __syncthreads();
        }
    }
}

// ---------------------------------------------------------------------------
// decoder: one block per (b,r), one-hot rid exploited as row lookup.
// ---------------------------------------------------------------------------
__global__ __launch_bounds__(256) void decoder_kernel(
    const float* __restrict__ traj, const float* __restrict__ Dz,
    const float* __restrict__ W_d1, const float* __restrict__ b_d1,
    const float* __restrict__ W_d2, const float* __restrict__ b_d2,
    float* __restrict__ y) {
    int br = blockIdx.x;
    int b = br >> 7;
    int r = br & 127;
    int tid = threadIdx.x;
    __shared__ __align__(16) float trajS[32 * L_];
    __shared__ __align__(16) float hS[32 * H_];
    __shared__ float dzS[D_];
    __shared__ float baseS[H_];

    int j = tid & 127;
    int th = tid >> 7;
    if (tid < D_) dzS[tid] = Dz[(size_t)br * D_ + tid];
    __syncthreads();

    float wcol[64];
    #pragma unroll
    for (int k = 0; k < 64; ++k) wcol[k] = W_d1[k * H_ + j];
    float wt = W_d1[128 * H_ + j];
    if (th == 0) {
        float a = b_d1[j] + W_d1[(129 + r) * H_ + j];
        #pragma unroll 4
        for (int k = 0; k < D_; ++k) a += dzS[k] * W_d1[(64 + k) * H_ + j];
        baseS[j] = a;
    }
    __syncthreads();
    float bb = baseS[j];

    for (int half = 0; half < 2; ++half) {
        for (int i = tid; i < 32 * L_; i += 256) {
            int tt = i >> 6, l = i & 63;
            trajS[i] = traj[(((size_t)b * T_ + half * 32 + tt) * R_ + r) * L_ + l];
        }
        __syncthreads();
        #pragma unroll
        for (int tt = 0; tt < 16; ++tt) {
            int tl = th * 16 + tt;
            int t = half * 32 + tl;
            float a = bb + (float)t * (1.f / 64.f) * wt;
            const float4* tr4 = (const float4*)(&trajS[tl * L_]);
            #pragma unroll
            for (int kb = 0; kb < 16; ++kb) {
                float4 tv = tr4[kb];
                a += tv.x * wcol[kb * 4 + 0] + tv.y * wcol[kb * 4 + 1] +
                     tv.z * wcol[kb * 4 + 2] + tv.w * wcol[kb * 4 + 3];
            }
            hS[tl * H_ + j] = silu_f(a);
        }
        __syncthreads();
        {
            int o = tid & 31, q = tid >> 5;
            float acc2[4];
            float bd2 = b_d2[o];
            #pragma unroll
            for (int u = 0; u < 4; ++u) acc2[u] = bd2;
            for (int jc = 0; jc < 4; ++jc) {
                float wreg[32];
                #pragma unroll
                for (int i2 = 0; i2 < 32; ++i2) wreg[i2] = W_d2[(jc * 32 + i2) * OUT_ + o];
                #pragma unroll
                for (int u = 0; u < 4; ++u) {
                    int tl = q * 4 + u;
                    const float4* h4 = (const float4*)(&hS[tl * H_ + jc * 32]);
                    float s2 = 0.f;
                    #pragma unroll
                    for (int w4 = 0; w4 < 8; ++w4) {
                        float4 hv = h4[w4];
                        s2 += hv.x * wreg[w4 * 4 + 0] + hv.y * wreg[w4 * 4 + 1] +
                              hv.z * wreg[w4 * 4 + 2] + hv.w * wreg[w4 * 4 + 3];
                    }
                    acc2[u] += s2;
                }
            }
            #pragma unroll
            for (int u = 0; u < 4; ++u) {
                int t = half * 32 + q * 4 + u;
                y[((size_t)br * T_ + t) * OUT_ + o] = acc2[u];
            }
        }
        __syncthreads();
    }
}

extern "C" void kernel_launch(void* const* d_in, const int* in_sizes, int n_in,
                              void* d_out, int out_size, void* d_ws, size_t ws_size,
                              hipStream_t stream) {
    const float* node_feats = (const float*)d_in[0];
    const float* eps_       = (const float*)d_in[1];
    const float* space_w    = (const float*)d_in[2];
    const int*   src        = (const int*)d_in[3];
    const int*   dst        = (const int*)d_in[4];
    const float* W_e1 = (const float*)d_in[5];
    const float* b_e1 = (const float*)d_in[6];
    const float* W_e2 = (const float*)d_in[7];
    const float* b_e2 = (const float*)d_in[8];
    const float* W_mu = (const float*)d_in[9];
    const float* W_sig = (const float*)d_in[10];
    const float* W_msg = (const float*)d_in[11];
    const float* W_self = (const float*)d_in[12];
    const float* W_dyn = (const float*)d_in[13];
    const float* b_ode = (const float*)d_in[14];
    const float* W_d1 = (const float*)d_in[15];
    const float* b_d1 = (const float*)d_in[16];
    const float* W_d2 = (const float*)d_in[17];
    const float* b_d2 = (const float*)d_in[18];
    float* out = (float*)d_out;

    float* f_ws = (float*)d_ws;
    float* Lz    = f_ws;                              // 65536
    float* Dz    = Lz + B_ * R_ * L_;                 // 65536
    float* dynb  = Dz + B_ * R_ * D_;                 // 65536
    float* traj  = dynb + B_ * R_ * L_;               // 4194304
    float* wperm = traj + (size_t)B_ * T_ * R_ * L_;  // 16384
    int* row_start = (int*)(wperm + B_ * ES_);        // 132
    int* esrcp     = row_start + 132;                 // 2048

    prep_kernel<<<1, 128, 0, stream>>>(src, dst, space_w, row_start, esrcp, wperm);
    encoder_kernel<<<B_ * R_, 256, 0, stream>>>(node_feats, eps_, W_e1, b_e1, W_e2, b_e2,
                                                W_mu, W_sig, W_dyn, Lz, Dz, dynb);
    ode_kernel<<<B_, 512, ODE_LDS, stream>>>(Lz, dynb, W_msg, W_self, b_ode,
                                             row_start, esrcp, wperm, traj);
    decoder_kernel<<<B_ * R_, 256, 0, stream>>>(traj, Dz, W_d1, b_d1, W_d2, b_d2, out);
}